// Round 4
// baseline (142.219 us; speedup 1.0000x reference)
//
#include <hip/hip_runtime.h>
#include <hip/hip_bf16.h>
#include <math.h>

typedef __attribute__((ext_vector_type(8))) __bf16 bf16x8;
typedef __attribute__((ext_vector_type(4))) __bf16 bf16x4;
typedef __attribute__((ext_vector_type(4))) float f32x4;

#define AST 136  // bf16 A-tile row stride (128+8): 2-way bank aliasing only (free)
#define HST 132  // fp32 h-tile row stride (128+4): 2-way bank aliasing only (free)

__device__ __forceinline__ float sigmoid_f(float v) {
  return __builtin_amdgcn_rcpf(1.f + __expf(-v));
}
__device__ __forceinline__ float tanh_f(float z) {
  float az = fabsf(z);
  float e = __expf(-2.f * az);
  float t = (1.f - e) * __builtin_amdgcn_rcpf(1.f + e);
  return copysignf(t, z);
}
__device__ __forceinline__ bf16x8 cvt8(float4 a, float4 b) {
  bf16x8 r;
  r[0] = (__bf16)a.x; r[1] = (__bf16)a.y; r[2] = (__bf16)a.z; r[3] = (__bf16)a.w;
  r[4] = (__bf16)b.x; r[5] = (__bf16)b.y; r[6] = (__bf16)b.z; r[7] = (__bf16)b.w;
  return r;
}
__device__ __forceinline__ bf16x4 cvt4(float4 a) {
  bf16x4 r;
  r[0] = (__bf16)a.x; r[1] = (__bf16)a.y; r[2] = (__bf16)a.z; r[3] = (__bf16)a.w;
  return r;
}

// Barrier that does NOT drain vmcnt: LDS ordering only needs lgkmcnt(0).
// Prefetch global loads issued before this stay in flight across it.
__device__ __forceinline__ void lds_barrier() {
  asm volatile("s_waitcnt lgkmcnt(0)\n\ts_barrier" ::: "memory");
}

// Block = 512 threads = 8 waves; wave w owns output cols [16w,16w+16) with all
// its weights (6 submats x 4 K-tiles) persistent in registers. Block owns full
// 128-col rows -> compulsory-only reads, full-line writes. Per 16-row tile:
// stage x/h (bf16 MFMA copy + fp32 h copy + att) into double-buffered LDS,
// lgkm-only barrier, MFMA + fused epilogue with zero global loads.
__global__ __launch_bounds__(512, 2) void augru_kernel(
    const float* __restrict__ x, const float* __restrict__ hp,
    const float* __restrict__ att,
    const float* __restrict__ Wx, const float* __restrict__ bx,
    const float* __restrict__ Wh, const float* __restrict__ bh,
    float* __restrict__ out) {
  __shared__ __bf16 alds[2][2][16 * AST];  // 17,408 B : bf16 x/h tiles
  __shared__ float  hlds[2][16 * HST];     // 16,896 B : fp32 h tile (epilogue)
  __shared__ float  attl[2][16];           //    128 B

  const int tid  = threadIdx.x;
  const int wave = tid >> 6;
  const int lane = tid & 63;
  const int quad = lane >> 4;
  const int l15  = lane & 15;
  const int col  = wave * 16 + l15;  // this lane's output column

  // ---- persistent B-fragments: m = gate*2 + (0:Wx,1:Wh), gates u=0,r=1,h=2.
  bf16x8 wf[6][4];
#pragma unroll
  for (int m = 0; m < 6; ++m) {
    const float* src = (m & 1) ? Wh : Wx;
    const float* wr  = src + ((m >> 1) * 128 + col) * 128 + quad * 8;
#pragma unroll
    for (int kt = 0; kt < 4; ++kt)
      wf[m][kt] = cvt8(*(const float4*)(wr + kt * 32), *(const float4*)(wr + kt * 32 + 4));
  }
  const float bu_  = bx[col] + bh[col];
  const float br_  = bx[128 + col] + bh[128 + col];
  const float bxh_ = bx[256 + col];
  const float bhh_ = bh[256 + col];

  // staging map: thread stages one x-float4 + one h-float4 per tile
  const int srow = tid >> 5;   // 0..15
  const int sj   = tid & 31;   // float4 within the 128-wide row
  const long sgoff = (long)srow * 128 + sj * 4;

  const int T = 8;
  const int tile0 = blockIdx.x * T;  // 512 blocks x 8 tiles x 16 rows = 65536

  // prefetch tile 0
  float4 xv = *(const float4*)(x  + (long)tile0 * 16 * 128 + sgoff);
  float4 hv = *(const float4*)(hp + (long)tile0 * 16 * 128 + sgoff);
  float  av = (tid < 16) ? att[tile0 * 16 + tid] : 0.f;

  for (int t = 0; t < T; ++t) {
    const int b  = t & 1;
    const int rb = (tile0 + t) * 16;

    // commit staged regs -> LDS buf b
    *(bf16x4*)&alds[b][0][srow * AST + sj * 4] = cvt4(xv);
    *(bf16x4*)&alds[b][1][srow * AST + sj * 4] = cvt4(hv);
    *(float4*)&hlds[b][srow * HST + sj * 4]    = hv;
    if (tid < 16) attl[b][tid] = av;

    // prefetch next tile — stays in flight across the lgkm-only barrier
    if (t + 1 < T) {
      xv = *(const float4*)(x  + (long)(rb + 16) * 128 + sgoff);
      hv = *(const float4*)(hp + (long)(rb + 16) * 128 + sgoff);
      av = (tid < 16) ? att[rb + 16 + tid] : 0.f;
    }

    lds_barrier();

    // A-fragments: A[m=l15][k=quad*8+j]
    bf16x8 xf[4], hf[4];
#pragma unroll
    for (int kt = 0; kt < 4; ++kt) {
      xf[kt] = *(const bf16x8*)&alds[b][0][l15 * AST + kt * 32 + quad * 8];
      hf[kt] = *(const bf16x8*)&alds[b][1][l15 * AST + kt * 32 + quad * 8];
    }

    f32x4 aU = (f32x4)0.f, aR = (f32x4)0.f, aHX = (f32x4)0.f, aHH = (f32x4)0.f;
#pragma unroll
    for (int kt = 0; kt < 4; ++kt) {
      aU  = __builtin_amdgcn_mfma_f32_16x16x32_bf16(xf[kt], wf[0][kt], aU, 0, 0, 0);
      aU  = __builtin_amdgcn_mfma_f32_16x16x32_bf16(hf[kt], wf[1][kt], aU, 0, 0, 0);
      aR  = __builtin_amdgcn_mfma_f32_16x16x32_bf16(xf[kt], wf[2][kt], aR, 0, 0, 0);
      aR  = __builtin_amdgcn_mfma_f32_16x16x32_bf16(hf[kt], wf[3][kt], aR, 0, 0, 0);
      aHX = __builtin_amdgcn_mfma_f32_16x16x32_bf16(xf[kt], wf[4][kt], aHX, 0, 0, 0);
      aHH = __builtin_amdgcn_mfma_f32_16x16x32_bf16(hf[kt], wf[5][kt], aHH, 0, 0, 0);
    }

    // ---- fused epilogue, zero global loads (h0/att from LDS).
    // C layout: col = l15-part, row = quad*4 + rr.
#pragma unroll
    for (int rr = 0; rr < 4; ++rr) {
      const int rl = quad * 4 + rr;
      float u  = sigmoid_f(aU[rr] + bu_);
      float r  = sigmoid_f(aR[rr] + br_);
      float ht = tanh_f(aHX[rr] + bxh_ + r * (aHH[rr] + bhh_));
      float ua = attl[b][rl] * u;
      float h0 = hlds[b][rl * HST + col];
      out[(long)(rb + rl) * 128 + col] = fmaf(ua, ht - h0, h0);
    }
  }
}

extern "C" void kernel_launch(void* const* d_in, const int* in_sizes, int n_in,
                              void* d_out, int out_size, void* d_ws, size_t ws_size,
                              hipStream_t stream) {
  const float* x   = (const float*)d_in[0];
  const float* hpv = (const float*)d_in[1];
  const float* att = (const float*)d_in[2];
  const float* Wx  = (const float*)d_in[3];
  const float* bx  = (const float*)d_in[4];
  const float* Wh  = (const float*)d_in[5];
  const float* bh  = (const float*)d_in[6];
  float* out = (float*)d_out;

  augru_kernel<<<512, 512, 0, stream>>>(x, hpv, att, Wx, bx, Wh, bh, out);
}